// Round 11
// baseline (609.766 us; speedup 1.0000x reference)
//
#include <hip/hip_runtime.h>
#include <math.h>

#define VOLN 256
#define N_ANG 16
#define DET_V 128
#define DET_U 128
#define DET_SP 5.0
#define DSI 400.0
#define DSD 800.0
#define N_STEP 192

// radius = sqrt(3)*256/2 ; t0 = DSI - radius ; dt = 2*radius/N_STEP
#define T0_F 178.29749663118372f
#define DT_F 2.3094010767585029f

// ---------------- fp32 trilerp, direct on input volume [z][y][x] ----------------
__device__ __forceinline__ float trilerp_f(const float* __restrict__ vol,
                                           float pz, float py, float px) {
    float z0f = floorf(pz), y0f = floorf(py), x0f = floorf(px);
    int z0 = (int)z0f, y0 = (int)y0f, x0 = (int)x0f;
    float fz = pz - z0f, fy = py - y0f, fx = px - x0f;

    // Fast path: whole 2x2x2 cell strictly in bounds.
    if (z0 >= 0 && z0 <= VOLN - 2 && y0 >= 0 && y0 <= VOLN - 2 && x0 >= 0 && x0 <= VOLN - 2) {
        const float* base = vol + (((z0 << 8) + y0) << 8) + x0;
        float v000 = base[0];
        float v001 = base[1];
        float v010 = base[VOLN];
        float v011 = base[VOLN + 1];
        float v100 = base[VOLN * VOLN];
        float v101 = base[VOLN * VOLN + 1];
        float v110 = base[VOLN * VOLN + VOLN];
        float v111 = base[VOLN * VOLN + VOLN + 1];
        float c00 = fmaf(fx, v001 - v000, v000);
        float c01 = fmaf(fx, v011 - v010, v010);
        float c10 = fmaf(fx, v101 - v100, v100);
        float c11 = fmaf(fx, v111 - v110, v110);
        float c0 = fmaf(fy, c01 - c00, c00);
        float c1 = fmaf(fy, c11 - c10, c10);
        return fmaf(fz, c1 - c0, c0);
    }

    // Entirely outside: no loads.
    if (z0 < -1 || z0 > VOLN - 1 || y0 < -1 || y0 > VOLN - 1 || x0 < -1 || x0 > VOLN - 1)
        return 0.0f;

    // Boundary slow path: per-corner mask (zero outside), matches reference.
    float acc = 0.0f;
    #pragma unroll
    for (int dz = 0; dz < 2; ++dz) {
        int iz = z0 + dz;
        if (iz < 0 || iz > VOLN - 1) continue;
        float wz = dz ? fz : (1.0f - fz);
        #pragma unroll
        for (int dy = 0; dy < 2; ++dy) {
            int iy = y0 + dy;
            if (iy < 0 || iy > VOLN - 1) continue;
            float wy = dy ? fy : (1.0f - fy);
            #pragma unroll
            for (int dx = 0; dx < 2; ++dx) {
                int ix = x0 + dx;
                if (ix < 0 || ix > VOLN - 1) continue;
                float wx = dx ? fx : (1.0f - fx);
                acc = fmaf(wz * wy * wx, vol[(((iz << 8) + iy) << 8) + ix], acc);
            }
        }
    }
    return acc;
}

// ---------------- ray setup ----------------
struct Ray { float dirz, diry, dirx, bz, by, bx; };

__device__ __forceinline__ Ray make_ray(int a, int u, int v) {
    double theta = (2.0 * M_PI / (double)N_ANG) * (double)a;
    double cth = cos(theta), sth = sin(theta);
    double uoff = ((double)u - (DET_U - 1) * 0.5) * DET_SP;
    double voff = ((double)v - (DET_V - 1) * 0.5) * DET_SP;

    double dzd = voff;
    double dyd = -DSD * sth + uoff * cth;
    double dxd = -DSD * cth - uoff * sth;
    double inv = 1.0 / sqrt(uoff * uoff + voff * voff + DSD * DSD);

    Ray r;
    r.dirz = (float)(dzd * inv);
    r.diry = (float)(dyd * inv);
    r.dirx = (float)(dxd * inv);
    const float half = (VOLN - 1) * 0.5f;
    r.bz = 0.0f + half;
    r.by = (float)(DSI * sth) + half;
    r.bx = (float)(DSI * cth) + half;
    return r;
}

// v-band XCD mapping (round-8 winner: FETCH 1.25 GB -> 0.36 GB at fp16).
// xcd = blockIdx.x & 7 (HW round-robin across XCDs): XCD k gets the contiguous
// detector v-band [16k, 16k+16) of EVERY angle -> all angles co-resident per
// XCD, per-XCD volume footprint is a z-localized wedge.
__device__ __forceinline__ void decode_block(int b, int tid, int& a, int& u, int& v) {
    int xcd = b & 7;
    int j = b >> 3;            // 0..127
    a = j & 15;
    int sub = j >> 4;          // 0..7
    int vpair = (xcd << 3) + sub;
    u = tid & 127;             // wave = 64 consecutive u
    v = (vpair << 1) + (tid >> 7);
}

// Single-dispatch fp32 projection: no workspace, no staging pipeline.
__global__ __launch_bounds__(256) void cone_proj_kernel(const float* __restrict__ vol,
                                                        float* __restrict__ out) {
    int a, u, v;
    decode_block(blockIdx.x, threadIdx.x, a, u, v);
    Ray r = make_ray(a, u, v);

    float acc = 0.0f;
    #pragma unroll 4
    for (int i = 0; i < N_STEP; ++i) {
        float t = fmaf((float)i + 0.5f, DT_F, T0_F);
        float pz = fmaf(t, r.dirz, r.bz);
        float py = fmaf(t, r.diry, r.by);
        float px = fmaf(t, r.dirx, r.bx);
        acc += trilerp_f(vol, pz, py, px);
    }
    out[(a << 14) + (v << 7) + u] = acc * DT_F;
}

extern "C" void kernel_launch(void* const* d_in, const int* in_sizes, int n_in,
                              void* d_out, int out_size, void* d_ws, size_t ws_size,
                              hipStream_t stream) {
    const float* vol = (const float*)d_in[0];
    float* out = (float*)d_out;
    const int total = N_ANG * DET_V * DET_U;   // 262144
    cone_proj_kernel<<<total / 256, 256, 0, stream>>>(vol, out);
}

// Round 12
// 566.039 us; speedup vs baseline: 1.0772x; 1.0772x over previous
//
#include <hip/hip_runtime.h>
#include <hip/hip_fp16.h>
#include <math.h>

#define VOLN 256
#define N_ANG 16
#define DET_V 128
#define DET_U 128
#define DET_SP 5.0
#define DSI 400.0
#define DSD 800.0
#define N_STEP 192
#define NSEG 2
#define SEG_STEPS (N_STEP / NSEG)   // 96

// radius = sqrt(3)*256/2 ; t0 = DSI - radius ; dt = 2*radius/N_STEP
#define T0_F 178.29749663118372f
#define DT_F 2.3094010767585029f

// ---------------- fp32 -> fp16 volume conversion (round-3/8/9 proven) ----------------
__global__ __launch_bounds__(256) void cvt_fp16_kernel(const float4* __restrict__ in,
                                                       uint2* __restrict__ out) {
    const int n4 = (VOLN * VOLN * VOLN) / 4;
    int stride = gridDim.x * blockDim.x;
    for (int i = blockIdx.x * blockDim.x + threadIdx.x; i < n4; i += stride) {
        float4 f = in[i];
        __half2 a = __floats2half2_rn(f.x, f.y);
        __half2 b = __floats2half2_rn(f.z, f.w);
        uint2 o;
        o.x = *reinterpret_cast<const unsigned int*>(&a);
        o.y = *reinterpret_cast<const unsigned int*>(&b);
        out[i] = o;
    }
}

// ---------------- fp16 trilerp over vol[z][y][x] ----------------
__device__ __forceinline__ float trilerp_h(const __half* __restrict__ vol,
                                           float pz, float py, float px) {
    float z0f = floorf(pz), y0f = floorf(py), x0f = floorf(px);
    int z0 = (int)z0f, y0 = (int)y0f, x0 = (int)x0f;
    float fz = pz - z0f, fy = py - y0f, fx = px - x0f;

    if (z0 >= 0 && z0 <= VOLN - 2 && y0 >= 0 && y0 <= VOLN - 2 && x0 >= 0 && x0 <= VOLN - 2) {
        const __half* base = vol + (((z0 << 8) + y0) << 8) + x0;
        float v000 = __half2float(base[0]);
        float v001 = __half2float(base[1]);
        float v010 = __half2float(base[VOLN]);
        float v011 = __half2float(base[VOLN + 1]);
        float v100 = __half2float(base[VOLN * VOLN]);
        float v101 = __half2float(base[VOLN * VOLN + 1]);
        float v110 = __half2float(base[VOLN * VOLN + VOLN]);
        float v111 = __half2float(base[VOLN * VOLN + VOLN + 1]);
        float c00 = fmaf(fx, v001 - v000, v000);
        float c01 = fmaf(fx, v011 - v010, v010);
        float c10 = fmaf(fx, v101 - v100, v100);
        float c11 = fmaf(fx, v111 - v110, v110);
        float c0 = fmaf(fy, c01 - c00, c00);
        float c1 = fmaf(fy, c11 - c10, c10);
        return fmaf(fz, c1 - c0, c0);
    }

    if (z0 < -1 || z0 > VOLN - 1 || y0 < -1 || y0 > VOLN - 1 || x0 < -1 || x0 > VOLN - 1)
        return 0.0f;

    float acc = 0.0f;
    #pragma unroll
    for (int dz = 0; dz < 2; ++dz) {
        int iz = z0 + dz;
        if (iz < 0 || iz > VOLN - 1) continue;
        float wz = dz ? fz : (1.0f - fz);
        #pragma unroll
        for (int dy = 0; dy < 2; ++dy) {
            int iy = y0 + dy;
            if (iy < 0 || iy > VOLN - 1) continue;
            float wy = dy ? fy : (1.0f - fy);
            #pragma unroll
            for (int dx = 0; dx < 2; ++dx) {
                int ix = x0 + dx;
                if (ix < 0 || ix > VOLN - 1) continue;
                float wx = dx ? fx : (1.0f - fx);
                float val = __half2float(vol[(((iz << 8) + iy) << 8) + ix]);
                acc = fmaf(wz * wy * wx, val, acc);
            }
        }
    }
    return acc;
}

// ---------------- fp32 trilerp (fallback, no workspace) ----------------
__device__ __forceinline__ float trilerp_f(const float* __restrict__ vol,
                                           float pz, float py, float px) {
    float z0f = floorf(pz), y0f = floorf(py), x0f = floorf(px);
    int z0 = (int)z0f, y0 = (int)y0f, x0 = (int)x0f;
    float fz = pz - z0f, fy = py - y0f, fx = px - x0f;
    if (z0 >= 0 && z0 <= VOLN - 2 && y0 >= 0 && y0 <= VOLN - 2 && x0 >= 0 && x0 <= VOLN - 2) {
        const float* base = vol + (((z0 << 8) + y0) << 8) + x0;
        float v000 = base[0], v001 = base[1];
        float v010 = base[VOLN], v011 = base[VOLN + 1];
        float v100 = base[VOLN * VOLN], v101 = base[VOLN * VOLN + 1];
        float v110 = base[VOLN * VOLN + VOLN], v111 = base[VOLN * VOLN + VOLN + 1];
        float c00 = fmaf(fx, v001 - v000, v000);
        float c01 = fmaf(fx, v011 - v010, v010);
        float c10 = fmaf(fx, v101 - v100, v100);
        float c11 = fmaf(fx, v111 - v110, v110);
        float c0 = fmaf(fy, c01 - c00, c00);
        float c1 = fmaf(fy, c11 - c10, c10);
        return fmaf(fz, c1 - c0, c0);
    }
    if (z0 < -1 || z0 > VOLN - 1 || y0 < -1 || y0 > VOLN - 1 || x0 < -1 || x0 > VOLN - 1)
        return 0.0f;
    float acc = 0.0f;
    #pragma unroll
    for (int dz = 0; dz < 2; ++dz) {
        int iz = z0 + dz;
        if (iz < 0 || iz > VOLN - 1) continue;
        float wz = dz ? fz : (1.0f - fz);
        #pragma unroll
        for (int dy = 0; dy < 2; ++dy) {
            int iy = y0 + dy;
            if (iy < 0 || iy > VOLN - 1) continue;
            float wy = dy ? fy : (1.0f - fy);
            #pragma unroll
            for (int dx = 0; dx < 2; ++dx) {
                int ix = x0 + dx;
                if (ix < 0 || ix > VOLN - 1) continue;
                float wx = dx ? fx : (1.0f - fx);
                acc = fmaf(wz * wy * wx, vol[(((iz << 8) + iy) << 8) + ix], acc);
            }
        }
    }
    return acc;
}

// ---------------- ray setup ----------------
struct Ray { float dirz, diry, dirx, bz, by, bx; };

__device__ __forceinline__ Ray make_ray(int a, int u, int v) {
    double theta = (2.0 * M_PI / (double)N_ANG) * (double)a;
    double cth = cos(theta), sth = sin(theta);
    double uoff = ((double)u - (DET_U - 1) * 0.5) * DET_SP;
    double voff = ((double)v - (DET_V - 1) * 0.5) * DET_SP;
    double dzd = voff;
    double dyd = -DSD * sth + uoff * cth;
    double dxd = -DSD * cth - uoff * sth;
    double inv = 1.0 / sqrt(uoff * uoff + voff * voff + DSD * DSD);
    Ray r;
    r.dirz = (float)(dzd * inv);
    r.diry = (float)(dyd * inv);
    r.dirx = (float)(dxd * inv);
    const float half = (VOLN - 1) * 0.5f;
    r.bz = 0.0f + half;
    r.by = (float)(DSI * sth) + half;
    r.bx = (float)(DSI * cth) + half;
    return r;
}

// v-band XCD mapping + 2-way t-segmentation. 2048 blocks (8/CU, all resident).
// xcd = b & 7: XCD k keeps the contiguous v-band [16k,16k+16) of EVERY angle
// (round-8 winner); each (angle, v-band) is covered by 2 blocks marching
// disjoint t-halves to double wave-level parallelism.
__device__ __forceinline__ void decode_block(int b, int tid,
                                             int& a, int& u, int& v, int& seg) {
    int xcd = b & 7;
    int j = b >> 3;            // 0..255
    a = j & 15;
    seg = (j >> 4) & 1;
    int sub = j >> 5;          // 0..7
    int vpair = (xcd << 3) + sub;
    u = tid & 127;             // wave = 64 consecutive u
    v = (vpair << 1) + (tid >> 7);
}

__global__ __launch_bounds__(256) void cone_proj_hseg_kernel(const __half* __restrict__ vol,
                                                             float* __restrict__ out) {
    int a, u, v, seg;
    decode_block(blockIdx.x, threadIdx.x, a, u, v, seg);
    Ray r = make_ray(a, u, v);

    float acc = 0.0f;
    int i0 = seg * SEG_STEPS;
    #pragma unroll 4
    for (int i = i0; i < i0 + SEG_STEPS; ++i) {
        float t = fmaf((float)i + 0.5f, DT_F, T0_F);
        float pz = fmaf(t, r.dirz, r.bz);
        float py = fmaf(t, r.diry, r.by);
        float px = fmaf(t, r.dirx, r.bx);
        acc += trilerp_h(vol, pz, py, px);
    }
    atomicAdd(&out[(a << 14) + (v << 7) + u], acc * DT_F);
}

// fp32 single-dispatch fallback (no workspace): round-11 path.
__global__ __launch_bounds__(256) void cone_proj_f_kernel(const float* __restrict__ vol,
                                                          float* __restrict__ out) {
    int a, u, v, seg;
    decode_block(blockIdx.x << 1, threadIdx.x, a, u, v, seg);  // seg=0 pattern
    a = ((blockIdx.x >> 3) & 15);
    int sub = blockIdx.x >> 7;
    int vpair = ((blockIdx.x & 7) << 3) + sub;
    u = threadIdx.x & 127;
    v = (vpair << 1) + (threadIdx.x >> 7);
    Ray r = make_ray(a, u, v);
    float acc = 0.0f;
    #pragma unroll 4
    for (int i = 0; i < N_STEP; ++i) {
        float t = fmaf((float)i + 0.5f, DT_F, T0_F);
        float pz = fmaf(t, r.dirz, r.bz);
        float py = fmaf(t, r.diry, r.by);
        float px = fmaf(t, r.dirx, r.bx);
        acc += trilerp_f(vol, pz, py, px);
    }
    out[(a << 14) + (v << 7) + u] = acc * DT_F;
}

extern "C" void kernel_launch(void* const* d_in, const int* in_sizes, int n_in,
                              void* d_out, int out_size, void* d_ws, size_t ws_size,
                              hipStream_t stream) {
    const float* vol = (const float*)d_in[0];
    float* out = (float*)d_out;
    const size_t need = (size_t)VOLN * VOLN * VOLN * sizeof(__half);   // 32 MiB

    if (ws_size >= need) {
        hipMemsetAsync(d_out, 0, (size_t)out_size * sizeof(float), stream);
        cvt_fp16_kernel<<<4096, 256, 0, stream>>>((const float4*)vol, (uint2*)d_ws);
        cone_proj_hseg_kernel<<<N_ANG * (DET_V / 2) * NSEG, 256, 0, stream>>>(
            (const __half*)d_ws, out);
    } else {
        cone_proj_f_kernel<<<N_ANG * (DET_V / 2), 256, 0, stream>>>(vol, out);
    }
}